// Round 13
// baseline (382.814 us; speedup 1.0000x reference)
//
#include <hip/hip_runtime.h>
#include <hip/hip_fp16.h>

typedef _Float16 f16;
typedef __attribute__((ext_vector_type(8))) _Float16 f16x8;
typedef __attribute__((ext_vector_type(4))) _Float16 f16x4;
typedef __attribute__((ext_vector_type(16))) float f32x16;

#define BM 128
#define BN 128
#define BK 64

__device__ __forceinline__ void gll16(const void* src, void* dst) {
  __builtin_amdgcn_global_load_lds((const __attribute__((address_space(1))) void*)src,
                                   (__attribute__((address_space(3))) void*)dst,
                                   16, 0, 0);
}

// C[m,n] = sum_k A[m,k] * B[n,k]  ("BT" form). m97-replica structure (R8/R11) with
// 32x32x16 MFMA (R13): same 128x128 tile, BK=64, single-buffered 32 KiB LDS,
// 256 thr (4 waves, 64x64/wave = 2x2 frags of 32x32), 2 barriers/K-tile,
// 3 blocks/CU cross-block overlap covers the vmcnt drain (m114; hard cap R10/R11).
// MFMA density: 16x ~8.07cyc vs 32x ~4.85cyc per wave-K-tile (-17% MFMA cycles).
// A/B frag: row/col = lane&31, k = (lane>>5)*8+i  (extends verified 16x16 pattern).
// C/D (m74/m101, HW-verified): col = lane&31, row = (reg&3)+8*(reg>>2)+4*(lane>>5).
// Swizzle: linear slot s of row r holds global slot s^(r&7) (0 conflicts measured;
// 16-lane phases hit 8 slots 2-way = free).
// MODE 0: C fp16   MODE 1: P=exp(acc*scale+mask) fp16 + row-sum partials (32/row)
// MODE 2: C fp32 = acc / lvec[z*M+row]
template<int MODE>
__global__ __launch_bounds__(256, 3)
void gemm_bt(const f16* __restrict__ Aall, const f16* __restrict__ Ball,
             void* __restrict__ Call,
             int M, int N, int K, int lda, int ldb, int ldc,
             long strideA, long strideB, long strideC,
             const float* __restrict__ maskAll, long strideMask,
             float* __restrict__ lvec, float scale)
{
  __shared__ __align__(16) f16 smA[BM * BK];   // 16 KB
  __shared__ __align__(16) f16 smB[BN * BK];   // 16 KB  -> 32 KiB total

  // T1: bijective XCD-aware remap (all grids have nwg % 8 == 0)
  unsigned gx = gridDim.x, gy = gridDim.y;
  unsigned id = (blockIdx.z * gy + blockIdx.y) * gx + blockIdx.x;
  unsigned nwg = gx * gy * gridDim.z;
  unsigned swz = (id & 7) * (nwg >> 3) + (id >> 3);
  unsigned bx = swz % gx, rem = swz / gx;
  unsigned by = rem % gy, bz = rem / gy;

  const int z = bz;
  const f16* A = Aall + (long)z * strideA;
  const f16* B = Ball + (long)z * strideB;

  const int tid  = threadIdx.x;
  const int wid  = tid >> 6;
  const int lane = tid & 63;
  const int wm = wid >> 1;        // 0..1 -> 64 rows of C
  const int wn = wid & 1;         // 0..1 -> 64 cols of C
  const int lc = lane & 31;       // row/col within 32x32 frag
  const int hi = lane >> 5;       // k-half selector for A/B frags

  const long brow = (long)by * BM;
  const long bcol = (long)bx * BN;
  const int  nt   = K / BK;

  f32x16 acc[2][2] = {};

  // stage one 128x64 f16 tile (16 KB = 1024 chunks of 16B; 4 chunks/thread).
  // chunk c: row=c>>3, linear slot=c&7, global slot=(c&7)^(row&7).
  auto stA = [&](int t) {
    #pragma unroll
    for (int i = 0; i < 4; ++i) {
      int c  = i * 256 + tid;
      int r  = c >> 3;
      int sl = (c & 7) ^ (r & 7);
      gll16(A + (brow + r) * (long)lda + t * BK + sl * 8, &smA[c * 8]);
    }
  };
  auto stB = [&](int t) {
    #pragma unroll
    for (int i = 0; i < 4; ++i) {
      int c  = i * 256 + tid;
      int r  = c >> 3;
      int sl = (c & 7) ^ (r & 7);
      gll16(B + (bcol + r) * (long)ldb + t * BK + sl * 8, &smB[c * 8]);
    }
  };
  // 32x32x16 fragment read: row r, K-step k16 (0..3): 8 f16 at k=k16*16+hi*8
  // -> global slot k16*2+hi, linear ^(r&7)
  auto ld32 = [&](const f16* base, int r, int k16) -> f16x8 {
    return *(const f16x8*)(base + r * BK + (((k16 << 1) + hi) ^ (r & 7)) * 8);
  };

  for (int t = 0; t < nt; ++t) {
    stA(t); stB(t);
    __syncthreads();                       // compiler drains vmcnt before s_barrier
    #pragma unroll
    for (int k16 = 0; k16 < 4; ++k16) {
      f16x8 a0 = ld32(smA, wm * 64 +      lc, k16);
      f16x8 a1 = ld32(smA, wm * 64 + 32 + lc, k16);
      f16x8 b0 = ld32(smB, wn * 64 +      lc, k16);
      f16x8 b1 = ld32(smB, wn * 64 + 32 + lc, k16);
      acc[0][0] = __builtin_amdgcn_mfma_f32_32x32x16_f16(a0, b0, acc[0][0], 0, 0, 0);
      acc[0][1] = __builtin_amdgcn_mfma_f32_32x32x16_f16(a0, b1, acc[0][1], 0, 0, 0);
      acc[1][0] = __builtin_amdgcn_mfma_f32_32x32x16_f16(a1, b0, acc[1][0], 0, 0, 0);
      acc[1][1] = __builtin_amdgcn_mfma_f32_32x32x16_f16(a1, b1, acc[1][1], 0, 0, 0);
    }
    __syncthreads();                       // all reads done before next stage
  }

  // C/D layout (m74/m101): col = lane&31, row = (reg&3) + 8*(reg>>2) + 4*(lane>>5)
  if (MODE == 0) {
    f16* C = (f16*)Call + (long)z * strideC;
    #pragma unroll
    for (int fm = 0; fm < 2; ++fm)
      #pragma unroll
      for (int fn = 0; fn < 2; ++fn)
        #pragma unroll
        for (int r16 = 0; r16 < 16; ++r16) {
          long grow = brow + wm * 64 + fm * 32 + (r16 & 3) + 8 * (r16 >> 2) + 4 * hi;
          long gcol = bcol + wn * 64 + fn * 32 + lc;
          C[grow * ldc + gcol] = (f16)acc[fm][fn][r16];
        }
  } else if (MODE == 1) {
    f16* C = (f16*)Call + (long)z * strideC;
    const float* mask = maskAll + (long)z * strideMask;
    #pragma unroll
    for (int fm = 0; fm < 2; ++fm)
      #pragma unroll
      for (int r16 = 0; r16 < 16; ++r16) {
        long grow = brow + wm * 64 + fm * 32 + (r16 & 3) + 8 * (r16 >> 2) + 4 * hi;
        float s = 0.f;
        #pragma unroll
        for (int fn = 0; fn < 2; ++fn) {
          long gcol = bcol + wn * 64 + fn * 32 + lc;
          float p = __expf(acc[fm][fn][r16] * scale + mask[grow * ldc + gcol]);
          C[grow * ldc + gcol] = (f16)p;
          s += p;
        }
        // row-sum over the 32 lanes of this half-wave (cols 0..31 of each frag)
        s += __shfl_xor(s, 1);
        s += __shfl_xor(s, 2);
        s += __shfl_xor(s, 4);
        s += __shfl_xor(s, 8);
        s += __shfl_xor(s, 16);
        if (lc == 0)
          lvec[((long)z * M + grow) * 32 + bx * 2 + wn] = s;
      }
  } else {
    float* C = (float*)Call + (long)z * strideC;
    #pragma unroll
    for (int fm = 0; fm < 2; ++fm)
      #pragma unroll
      for (int r16 = 0; r16 < 16; ++r16) {
        long grow = brow + wm * 64 + fm * 32 + (r16 & 3) + 8 * (r16 >> 2) + 4 * hi;
        float inv = 1.0f / lvec[(long)z * M + grow];
        #pragma unroll
        for (int fn = 0; fn < 2; ++fn) {
          long gcol = bcol + wn * 64 + fn * 32 + lc;
          C[grow * ldc + gcol] = acc[fm][fn][r16] * inv;
        }
      }
  }
}

// grid-strided fp32->fp16 convert: q, k, v, Wv  (Wq/Wk handled by transW)
__global__ void cvt_all(const float* __restrict__ q, const float* __restrict__ k,
                        const float* __restrict__ v, const float* __restrict__ Wv,
                        f16* __restrict__ qf, f16* __restrict__ kf, f16* __restrict__ vf,
                        f16* __restrict__ Wvf)
{
  const long NQ4 = 4194304, NW4 = 262144;       // float4 counts
  const long total = 3 * NQ4 + NW4;
  for (long i = (long)blockIdx.x * blockDim.x + threadIdx.x; i < total;
       i += (long)gridDim.x * blockDim.x) {
    const float* src; f16* dst; long j = i;
    if      (j <     NQ4) { src = q;  dst = qf; }
    else if (j < 2 * NQ4) { src = k;  dst = kf;  j -= NQ4; }
    else if (j < 3 * NQ4) { src = v;  dst = vf;  j -= 2 * NQ4; }
    else                  { src = Wv; dst = Wvf; j -= 3 * NQ4; }
    float4 vv = ((const float4*)src)[j];
    f16x4 o;
    o[0] = (f16)vv.x; o[1] = (f16)vv.y; o[2] = (f16)vv.z; o[3] = (f16)vv.w;
    ((f16x4*)dst)[j] = o;
  }
}

// 64x64-tile LDS transpose + fp32->fp16: WT[d][h] = (f16)W[h][d], for Wq and Wk.
__global__ void transW(const float* __restrict__ Wq, const float* __restrict__ Wk,
                       f16* __restrict__ WqT, f16* __restrict__ WkT)
{
  __shared__ f16 t[64][65];
  const float* W  = blockIdx.z ? Wk : Wq;
  f16*         WT = blockIdx.z ? WkT : WqT;
  const int h0 = blockIdx.y * 64, d0 = blockIdx.x * 64;
  const int tx = threadIdx.x & 15, ty = threadIdx.x >> 4;   // 16 x 16
  #pragma unroll
  for (int p = 0; p < 4; ++p) {
    int h = ty + p * 16;
    float4 vv = *(const float4*)(W + (long)(h0 + h) * 1024 + d0 + tx * 4);
    t[tx * 4 + 0][h] = (f16)vv.x;
    t[tx * 4 + 1][h] = (f16)vv.y;
    t[tx * 4 + 2][h] = (f16)vv.z;
    t[tx * 4 + 3][h] = (f16)vv.w;
  }
  __syncthreads();
  #pragma unroll
  for (int p = 0; p < 4; ++p) {
    int d = ty + p * 16;
    f16x4 o;
    o[0] = t[d][tx * 4 + 0];
    o[1] = t[d][tx * 4 + 1];
    o[2] = t[d][tx * 4 + 2];
    o[3] = t[d][tx * 4 + 3];
    *(f16x4*)(WT + (long)(d0 + d) * 1024 + h0 + tx * 4) = o;
  }
}

__global__ void reduce_l(const float* __restrict__ lpart, float* __restrict__ lsum, int n) {
  int i = blockIdx.x * blockDim.x + threadIdx.x;
  if (i < n) {
    float s = 0.f;
    #pragma unroll
    for (int j = 0; j < 32; ++j) s += lpart[(long)i * 32 + j];
    lsum[i] = s;
  }
}

extern "C" void kernel_launch(void* const* d_in, const int* in_sizes, int n_in,
                              void* d_out, int out_size, void* d_ws, size_t ws_size,
                              hipStream_t stream)
{
  const float* q    = (const float*)d_in[0];
  const float* k    = (const float*)d_in[1];
  const float* v    = (const float*)d_in[2];
  const float* mask = (const float*)d_in[3];
  const float* Wq   = (const float*)d_in[4];
  const float* Wk   = (const float*)d_in[5];
  const float* Wv   = (const float*)d_in[6];
  float* out = (float*)d_out;
  char*  ws  = (char*)d_ws;

  // workspace layout (bytes). qf and vf are dead after qg/vpT -> Pm overwrites
  // [0,64MB) = qf+vf. kf (needed by scores) lives above that region.
  f16*   qf    = (f16*)(ws + 0);           // 32 MB   (dead after qg)
  f16*   vf    = (f16*)(ws + 33554432);    // 32 MB   (dead after vpT)
  f16*   Pm    = (f16*)(ws + 0);           // 64 MB   (over qf+vf)
  f16*   kf    = (f16*)(ws + 67108864);    // 32 MB   (raw k fp16, read by scores)
  f16*   Wvf   = (f16*)(ws + 100663296);   // 2 MB
  f16*   WqT   = (f16*)(ws + 102760448);   // 2 MB    WqT[d][h]
  f16*   WkT   = (f16*)(ws + 104857600);   // 2 MB    WkT[d][h]
  f16*   Gt    = (f16*)(ws + 106954752);   // 2 MB    Gt[d'][d] = sum_h Wk[h,d']Wq[h,d]
  f16*   qg    = (f16*)(ws + 109051904);   // 32 MB   qg[l,d'] = sum_d q[l,d] G[d,d']
  f16*   vpT   = (f16*)(ws + 142606336);   // 32 MB   (stored H x J, transposed)
  float* lpart = (float*)(ws + 176160768); // 2 MB
  float* lsum  = (float*)(ws + 178257920); // 64 KB

  const long L = 2048, J = 2048, D = 1024, H = 1024;

  // 1) converts: q,k,v,Wv fp32->fp16 ; Wq,Wk fp32->fp16 TRANSPOSED
  cvt_all<<<dim3(2048), dim3(256), 0, stream>>>(q, k, v, Wv, qf, kf, vf, Wvf);
  transW<<<dim3(16, 16, 2), dim3(256), 0, stream>>>(Wq, Wk, WqT, WkT);

  // 2) Gt[d',d] = sum_h WkT[d',h] * WqT[d,h]   M=N=K=1024 (tiny, 2.1 GF)
  gemm_bt<0><<<dim3(1024 / BN, 1024 / BM, 1), dim3(256), 0, stream>>>(
      WkT, WqT, Gt, 1024, 1024, 1024, 1024, 1024, 1024,
      0, 0, 0, nullptr, 0, nullptr, 0.f);

  // 3) qg[l,d'] = sum_d qf[l,d] * Gt[d',d]   M=16384 N=1024 K=1024
  gemm_bt<0><<<dim3(1024 / BN, 16384 / BM, 1), dim3(256), 0, stream>>>(
      qf, Gt, qg, 16384, 1024, 1024, 1024, 1024, 1024,
      0, 0, 0, nullptr, 0, nullptr, 0.f);

  // 4) vpT[b][h,j] = sum_d Wv[h,d] * v[b][j,d]   M=1024 N=2048 K=1024, batched
  gemm_bt<0><<<dim3(2048 / BN, 1024 / BM, 8), dim3(256), 0, stream>>>(
      Wvf, vf, vpT, 1024, 2048, 1024, 1024, 1024, 2048,
      0, J * D, H * J, nullptr, 0, nullptr, 0.f);

  // 5) P[b][l,j] = exp(qg.kf^T / 32 + mask), fp16, + row-sum partials
  //    (scores = qp.kp^T by associativity: qg = q.Wq^T.Wk, kf = raw k)
  gemm_bt<1><<<dim3(2048 / BN, 2048 / BM, 8), dim3(256), 0, stream>>>(
      qg, kf, Pm, 2048, 2048, 1024, 1024, 1024, 2048,
      L * D, J * D, L * J, mask, L * J, lpart, 0.03125f);

  reduce_l<<<dim3(16384 / 256), dim3(256), 0, stream>>>(lpart, lsum, 16384);

  // 6) out[b][l,h] = (sum_j P[l,j] * vpT[h,j]) / l[b,l]   M=2048 N=1024 K=2048
  gemm_bt<2><<<dim3(1024 / BN, 2048 / BM, 8), dim3(256), 0, stream>>>(
      Pm, vpT, out, 2048, 1024, 2048, 2048, 2048, 1024,
      L * J, H * J, L * H, nullptr, 0, lsum, 0.f);
}

// Round 14
// 337.355 us; speedup vs baseline: 1.1348x; 1.1348x over previous
//
#include <hip/hip_runtime.h>
#include <hip/hip_fp16.h>

typedef _Float16 f16;
typedef __attribute__((ext_vector_type(8))) _Float16 f16x8;
typedef __attribute__((ext_vector_type(4))) _Float16 f16x4;
typedef __attribute__((ext_vector_type(4))) float f32x4;

#define BM 128
#define BN 128
#define BK 64

__device__ __forceinline__ void gll16(const void* src, void* dst) {
  __builtin_amdgcn_global_load_lds((const __attribute__((address_space(1))) void*)src,
                                   (__attribute__((address_space(3))) void*)dst,
                                   16, 0, 0);
}

// C[m,n] = sum_k A[m,k] * B[n,k]  ("BT" form). m97-replica structure (R8/R11 proven
// optimum, reverted from R13's 32x32 experiment — 8.39M bank conflicts, +33us):
// 128x128 tile, BK=64, single-buffered 32 KiB LDS, 256 thr (4 waves, 64x64/wave),
// 2 barriers/K-tile; vmcnt drain covered by 3 blocks/CU cross-block overlap (m114;
// hard residency cap measured in R10/R11 — launch_bounds 4/6 don't raise it).
// 16x16x32 MFMA: the only shape whose ds_read pattern measures 0 conflicts here.
// Swizzle: linear slot s of row r holds global slot s^(r&7).
// MODE 0: C fp16   MODE 1: P=exp(acc*scale+mask) fp16 + row-sum partials (32/row)
// MODE 2: C fp32 = acc / lvec[z*M+row]
template<int MODE>
__global__ __launch_bounds__(256, 3)
void gemm_bt(const f16* __restrict__ Aall, const f16* __restrict__ Ball,
             void* __restrict__ Call,
             int M, int N, int K, int lda, int ldb, int ldc,
             long strideA, long strideB, long strideC,
             const float* __restrict__ maskAll, long strideMask,
             float* __restrict__ lvec, float scale)
{
  __shared__ __align__(16) f16 smA[BM * BK];   // 16 KB
  __shared__ __align__(16) f16 smB[BN * BK];   // 16 KB  -> 32 KiB total

  // T1: bijective XCD-aware remap (all grids have nwg % 8 == 0)
  unsigned gx = gridDim.x, gy = gridDim.y;
  unsigned id = (blockIdx.z * gy + blockIdx.y) * gx + blockIdx.x;
  unsigned nwg = gx * gy * gridDim.z;
  unsigned swz = (id & 7) * (nwg >> 3) + (id >> 3);
  unsigned bx = swz % gx, rem = swz / gx;
  unsigned by = rem % gy, bz = rem / gy;

  const int z = bz;
  const f16* A = Aall + (long)z * strideA;
  const f16* B = Ball + (long)z * strideB;

  const int tid  = threadIdx.x;
  const int wid  = tid >> 6;
  const int lane = tid & 63;
  const int wm = wid >> 1;        // 0..1 -> 64 rows of C
  const int wn = wid & 1;         // 0..1 -> 64 cols of C
  const int lr = lane & 15;
  const int g  = lane >> 4;       // k-slot 0..3 (8 f16 each)

  const long brow = (long)by * BM;
  const long bcol = (long)bx * BN;
  const int  nt   = K / BK;

  f32x4 acc[4][4] = {};

  // stage one 128x64 f16 tile (16 KB = 1024 chunks of 16B; 4 chunks/thread).
  // chunk c: row=c>>3, linear slot=c&7, global slot=(c&7)^(row&7).
  auto stA = [&](int t) {
    #pragma unroll
    for (int i = 0; i < 4; ++i) {
      int c  = i * 256 + tid;
      int r  = c >> 3;
      int sl = (c & 7) ^ (r & 7);
      gll16(A + (brow + r) * (long)lda + t * BK + sl * 8, &smA[c * 8]);
    }
  };
  auto stB = [&](int t) {
    #pragma unroll
    for (int i = 0; i < 4; ++i) {
      int c  = i * 256 + tid;
      int r  = c >> 3;
      int sl = (c & 7) ^ (r & 7);
      gll16(B + (bcol + r) * (long)ldb + t * BK + sl * 8, &smB[c * 8]);
    }
  };

  for (int t = 0; t < nt; ++t) {
    stA(t); stB(t);
    __syncthreads();                       // compiler drains vmcnt before s_barrier
    f16x8 af[8], bf[8];
    #pragma unroll
    for (int fm = 0; fm < 4; ++fm)
      #pragma unroll
      for (int ks = 0; ks < 2; ++ks) {
        int r = wm * 64 + fm * 16 + lr;
        af[fm * 2 + ks] = *(const f16x8*)(smA + r * BK + ((ks * 4 + g) ^ (r & 7)) * 8);
      }
    #pragma unroll
    for (int fn = 0; fn < 4; ++fn)
      #pragma unroll
      for (int ks = 0; ks < 2; ++ks) {
        int r = wn * 64 + fn * 16 + lr;
        bf[fn * 2 + ks] = *(const f16x8*)(smB + r * BK + ((ks * 4 + g) ^ (r & 7)) * 8);
      }
    #pragma unroll
    for (int fm = 0; fm < 4; ++fm)
      #pragma unroll
      for (int fn = 0; fn < 4; ++fn)
        #pragma unroll
        for (int ks = 0; ks < 2; ++ks)
          acc[fm][fn] = __builtin_amdgcn_mfma_f32_16x16x32_f16(
              af[fm * 2 + ks], bf[fn * 2 + ks], acc[fm][fn], 0, 0, 0);
    __syncthreads();                       // all reads done before next stage
  }

  // C/D layout (m89-verified): col = lane&15, row = (lane>>4)*4 + reg
  const int rb = (lane >> 4) * 4;

  if (MODE == 0) {
    f16* C = (f16*)Call + (long)z * strideC;
    #pragma unroll
    for (int m = 0; m < 4; ++m)
      #pragma unroll
      for (int j = 0; j < 4; ++j) {
        long grow = brow + wm * 64 + m * 16 + rb + j;
        #pragma unroll
        for (int n = 0; n < 4; ++n) {
          long gcol = bcol + wn * 64 + n * 16 + lr;
          C[grow * ldc + gcol] = (f16)acc[m][n][j];
        }
      }
  } else if (MODE == 1) {
    f16* C = (f16*)Call + (long)z * strideC;
    const float* mask = maskAll + (long)z * strideMask;
    #pragma unroll
    for (int m = 0; m < 4; ++m)
      #pragma unroll
      for (int j = 0; j < 4; ++j) {
        long grow = brow + wm * 64 + m * 16 + rb + j;
        float s = 0.f;
        #pragma unroll
        for (int n = 0; n < 4; ++n) {
          long gcol = bcol + wn * 64 + n * 16 + lr;
          float p = __expf(acc[m][n][j] * scale + mask[grow * ldc + gcol]);
          C[grow * ldc + gcol] = (f16)p;
          s += p;
        }
        s += __shfl_xor(s, 1);
        s += __shfl_xor(s, 2);
        s += __shfl_xor(s, 4);
        s += __shfl_xor(s, 8);
        if (lr == 0)
          lvec[((long)z * M + grow) * 32 + bx * 2 + wn] = s;
      }
  } else {
    float* C = (float*)Call + (long)z * strideC;
    #pragma unroll
    for (int m = 0; m < 4; ++m)
      #pragma unroll
      for (int j = 0; j < 4; ++j) {
        long grow = brow + wm * 64 + m * 16 + rb + j;
        float inv = 1.0f / lvec[(long)z * M + grow];
        #pragma unroll
        for (int n = 0; n < 4; ++n) {
          long gcol = bcol + wn * 64 + n * 16 + lr;
          C[grow * ldc + gcol] = acc[m][n][j] * inv;
        }
      }
  }
}

// grid-strided fp32->fp16 convert: q, k, v, Wv  (Wq/Wk handled by transW)
__global__ void cvt_all(const float* __restrict__ q, const float* __restrict__ k,
                        const float* __restrict__ v, const float* __restrict__ Wv,
                        f16* __restrict__ qf, f16* __restrict__ kf, f16* __restrict__ vf,
                        f16* __restrict__ Wvf)
{
  const long NQ4 = 4194304, NW4 = 262144;       // float4 counts
  const long total = 3 * NQ4 + NW4;
  for (long i = (long)blockIdx.x * blockDim.x + threadIdx.x; i < total;
       i += (long)gridDim.x * blockDim.x) {
    const float* src; f16* dst; long j = i;
    if      (j <     NQ4) { src = q;  dst = qf; }
    else if (j < 2 * NQ4) { src = k;  dst = kf;  j -= NQ4; }
    else if (j < 3 * NQ4) { src = v;  dst = vf;  j -= 2 * NQ4; }
    else                  { src = Wv; dst = Wvf; j -= 3 * NQ4; }
    float4 vv = ((const float4*)src)[j];
    f16x4 o;
    o[0] = (f16)vv.x; o[1] = (f16)vv.y; o[2] = (f16)vv.z; o[3] = (f16)vv.w;
    ((f16x4*)dst)[j] = o;
  }
}

// 64x64-tile LDS transpose + fp32->fp16: WT[d][h] = (f16)W[h][d], for Wq and Wk.
__global__ void transW(const float* __restrict__ Wq, const float* __restrict__ Wk,
                       f16* __restrict__ WqT, f16* __restrict__ WkT)
{
  __shared__ f16 t[64][65];
  const float* W  = blockIdx.z ? Wk : Wq;
  f16*         WT = blockIdx.z ? WkT : WqT;
  const int h0 = blockIdx.y * 64, d0 = blockIdx.x * 64;
  const int tx = threadIdx.x & 15, ty = threadIdx.x >> 4;   // 16 x 16
  #pragma unroll
  for (int p = 0; p < 4; ++p) {
    int h = ty + p * 16;
    float4 vv = *(const float4*)(W + (long)(h0 + h) * 1024 + d0 + tx * 4);
    t[tx * 4 + 0][h] = (f16)vv.x;
    t[tx * 4 + 1][h] = (f16)vv.y;
    t[tx * 4 + 2][h] = (f16)vv.z;
    t[tx * 4 + 3][h] = (f16)vv.w;
  }
  __syncthreads();
  #pragma unroll
  for (int p = 0; p < 4; ++p) {
    int d = ty + p * 16;
    f16x4 o;
    o[0] = t[d][tx * 4 + 0];
    o[1] = t[d][tx * 4 + 1];
    o[2] = t[d][tx * 4 + 2];
    o[3] = t[d][tx * 4 + 3];
    *(f16x4*)(WT + (long)(d0 + d) * 1024 + h0 + tx * 4) = o;
  }
}

__global__ void reduce_l(const float* __restrict__ lpart, float* __restrict__ lsum, int n) {
  int i = blockIdx.x * blockDim.x + threadIdx.x;
  if (i < n) {
    float s = 0.f;
    #pragma unroll
    for (int j = 0; j < 32; ++j) s += lpart[(long)i * 32 + j];
    lsum[i] = s;
  }
}

extern "C" void kernel_launch(void* const* d_in, const int* in_sizes, int n_in,
                              void* d_out, int out_size, void* d_ws, size_t ws_size,
                              hipStream_t stream)
{
  const float* q    = (const float*)d_in[0];
  const float* k    = (const float*)d_in[1];
  const float* v    = (const float*)d_in[2];
  const float* mask = (const float*)d_in[3];
  const float* Wq   = (const float*)d_in[4];
  const float* Wk   = (const float*)d_in[5];
  const float* Wv   = (const float*)d_in[6];
  float* out = (float*)d_out;
  char*  ws  = (char*)d_ws;

  // workspace layout (bytes). qf and vf are dead after qg/vpT -> Pm overwrites
  // [0,64MB) = qf+vf. kf (needed by scores) lives above that region.
  f16*   qf    = (f16*)(ws + 0);           // 32 MB   (dead after qg)
  f16*   vf    = (f16*)(ws + 33554432);    // 32 MB   (dead after vpT)
  f16*   Pm    = (f16*)(ws + 0);           // 64 MB   (over qf+vf)
  f16*   kf    = (f16*)(ws + 67108864);    // 32 MB   (raw k fp16, read by scores)
  f16*   Wvf   = (f16*)(ws + 100663296);   // 2 MB
  f16*   WqT   = (f16*)(ws + 102760448);   // 2 MB    WqT[d][h]
  f16*   WkT   = (f16*)(ws + 104857600);   // 2 MB    WkT[d][h]
  f16*   Gt    = (f16*)(ws + 106954752);   // 2 MB    Gt[d'][d] = sum_h Wk[h,d']Wq[h,d]
  f16*   qg    = (f16*)(ws + 109051904);   // 32 MB   qg[l,d'] = sum_d q[l,d] G[d,d']
  f16*   vpT   = (f16*)(ws + 142606336);   // 32 MB   (stored H x J, transposed)
  float* lpart = (float*)(ws + 176160768); // 2 MB
  float* lsum  = (float*)(ws + 178257920); // 64 KB

  const long L = 2048, J = 2048, D = 1024, H = 1024;

  // 1) converts: q,k,v,Wv fp32->fp16 ; Wq,Wk fp32->fp16 TRANSPOSED
  cvt_all<<<dim3(2048), dim3(256), 0, stream>>>(q, k, v, Wv, qf, kf, vf, Wvf);
  transW<<<dim3(16, 16, 2), dim3(256), 0, stream>>>(Wq, Wk, WqT, WkT);

  // 2) Gt[d',d] = sum_h WkT[d',h] * WqT[d,h]   M=N=K=1024 (tiny, 2.1 GF)
  gemm_bt<0><<<dim3(1024 / BN, 1024 / BM, 1), dim3(256), 0, stream>>>(
      WkT, WqT, Gt, 1024, 1024, 1024, 1024, 1024, 1024,
      0, 0, 0, nullptr, 0, nullptr, 0.f);

  // 3) qg[l,d'] = sum_d qf[l,d] * Gt[d',d]   M=16384 N=1024 K=1024
  gemm_bt<0><<<dim3(1024 / BN, 16384 / BM, 1), dim3(256), 0, stream>>>(
      qf, Gt, qg, 16384, 1024, 1024, 1024, 1024, 1024,
      0, 0, 0, nullptr, 0, nullptr, 0.f);

  // 4) vpT[b][h,j] = sum_d Wv[h,d] * v[b][j,d]   M=1024 N=2048 K=1024, batched
  gemm_bt<0><<<dim3(2048 / BN, 1024 / BM, 8), dim3(256), 0, stream>>>(
      Wvf, vf, vpT, 1024, 2048, 1024, 1024, 1024, 2048,
      0, J * D, H * J, nullptr, 0, nullptr, 0.f);

  // 5) P[b][l,j] = exp(qg.kf^T / 32 + mask), fp16, + row-sum partials
  //    (scores = qp.kp^T by associativity: qg = q.Wq^T.Wk, kf = raw k)
  gemm_bt<1><<<dim3(2048 / BN, 2048 / BM, 8), dim3(256), 0, stream>>>(
      qg, kf, Pm, 2048, 2048, 1024, 1024, 1024, 2048,
      L * D, J * D, L * J, mask, L * J, lpart, 0.03125f);

  reduce_l<<<dim3(16384 / 256), dim3(256), 0, stream>>>(lpart, lsum, 16384);

  // 6) out[b][l,h] = (sum_j P[l,j] * vpT[h,j]) / l[b,l]   M=2048 N=1024 K=2048
  gemm_bt<2><<<dim3(1024 / BN, 2048 / BM, 8), dim3(256), 0, stream>>>(
      Pm, vpT, out, 2048, 1024, 2048, 2048, 2048, 1024,
      L * J, H * J, L * H, nullptr, 0, lsum, 0.f);
}

// Round 15
// 332.600 us; speedup vs baseline: 1.1510x; 1.0143x over previous
//
#include <hip/hip_runtime.h>
#include <hip/hip_fp16.h>

typedef _Float16 f16;
typedef __attribute__((ext_vector_type(8))) _Float16 f16x8;
typedef __attribute__((ext_vector_type(4))) _Float16 f16x4;
typedef __attribute__((ext_vector_type(4))) float f32x4;

#define BM 128
#define BN 128
#define BK 64

__device__ __forceinline__ void gll16(const void* src, void* dst) {
  __builtin_amdgcn_global_load_lds((const __attribute__((address_space(1))) void*)src,
                                   (__attribute__((address_space(3))) void*)dst,
                                   16, 0, 0);
}

// C[m,n] = sum_k A[m,k] * B[n,k]  ("BT" form). m97-replica structure (R8/R11/R14
// proven optimum): 128x128 tile, BK=64, single-buffered 32 KiB LDS, 256 thr
// (4 waves, 64x64/wave), 2 barriers/K-tile; vmcnt drain covered by 3 blocks/CU
// cross-block overlap (m114; hard residency cap measured R10/R11).
// R15: LDS-bounced epilogues. The MFMA C/D lane-map makes direct mask-loads /
// P/out-stores ~25%-coalesced (4 scattered 64B segs per wave-instr); scores'
// dispatch time == traffic/achieved-BW (204MB @ 1.78 TB/s = 114us), so epilogue
// BW is the binding constraint. After the K-loop smA/smB are dead: bounce mask
// (fp16 in, exact for this input) and P/out tiles through LDS; coop passes do
// fully-coalesced 1-2KB/wave global accesses. Col-XOR swizzles per width keep
// LDS at <=2-way (free, m136).
// Swizzle (K-loop): linear slot s of row r holds global slot s^(r&7) (0 conflicts).
// MODE 0: C fp16   MODE 1: P=exp(acc*scale+mask) fp16 + row-sum partials (32/row)
// MODE 2: C fp32 = acc / lvec[z*M+row]
template<int MODE>
__global__ __launch_bounds__(256, 3)
void gemm_bt(const f16* __restrict__ Aall, const f16* __restrict__ Ball,
             void* __restrict__ Call,
             int M, int N, int K, int lda, int ldb, int ldc,
             long strideA, long strideB, long strideC,
             const float* __restrict__ maskAll, long strideMask,
             float* __restrict__ lvec, float scale)
{
  __shared__ __align__(16) f16 smbuf[BM * BK + BN * BK];   // 32 KiB total
  f16* smA = smbuf;
  f16* smB = smbuf + BM * BK;

  // T1: bijective XCD-aware remap (all grids have nwg % 8 == 0)
  unsigned gx = gridDim.x, gy = gridDim.y;
  unsigned id = (blockIdx.z * gy + blockIdx.y) * gx + blockIdx.x;
  unsigned nwg = gx * gy * gridDim.z;
  unsigned swz = (id & 7) * (nwg >> 3) + (id >> 3);
  unsigned bx = swz % gx, rem = swz / gx;
  unsigned by = rem % gy, bz = rem / gy;

  const int z = bz;
  const f16* A = Aall + (long)z * strideA;
  const f16* B = Ball + (long)z * strideB;

  const int tid  = threadIdx.x;
  const int wid  = tid >> 6;
  const int lane = tid & 63;
  const int wm = wid >> 1;        // 0..1 -> 64 rows of C
  const int wn = wid & 1;         // 0..1 -> 64 cols of C
  const int lr = lane & 15;
  const int g  = lane >> 4;       // k-slot 0..3 (8 f16 each)

  const long brow = (long)by * BM;
  const long bcol = (long)bx * BN;
  const int  nt   = K / BK;

  f32x4 acc[4][4] = {};

  // stage one 128x64 f16 tile (16 KB = 1024 chunks of 16B; 4 chunks/thread).
  // chunk c: row=c>>3, linear slot=c&7, global slot=(c&7)^(row&7).
  auto stA = [&](int t) {
    #pragma unroll
    for (int i = 0; i < 4; ++i) {
      int c  = i * 256 + tid;
      int r  = c >> 3;
      int sl = (c & 7) ^ (r & 7);
      gll16(A + (brow + r) * (long)lda + t * BK + sl * 8, &smA[c * 8]);
    }
  };
  auto stB = [&](int t) {
    #pragma unroll
    for (int i = 0; i < 4; ++i) {
      int c  = i * 256 + tid;
      int r  = c >> 3;
      int sl = (c & 7) ^ (r & 7);
      gll16(B + (bcol + r) * (long)ldb + t * BK + sl * 8, &smB[c * 8]);
    }
  };

  for (int t = 0; t < nt; ++t) {
    stA(t); stB(t);
    __syncthreads();                       // compiler drains vmcnt before s_barrier
    f16x8 af[8], bf[8];
    #pragma unroll
    for (int fm = 0; fm < 4; ++fm)
      #pragma unroll
      for (int ks = 0; ks < 2; ++ks) {
        int r = wm * 64 + fm * 16 + lr;
        af[fm * 2 + ks] = *(const f16x8*)(smA + r * BK + ((ks * 4 + g) ^ (r & 7)) * 8);
      }
    #pragma unroll
    for (int fn = 0; fn < 4; ++fn)
      #pragma unroll
      for (int ks = 0; ks < 2; ++ks) {
        int r = wn * 64 + fn * 16 + lr;
        bf[fn * 2 + ks] = *(const f16x8*)(smB + r * BK + ((ks * 4 + g) ^ (r & 7)) * 8);
      }
    #pragma unroll
    for (int fm = 0; fm < 4; ++fm)
      #pragma unroll
      for (int fn = 0; fn < 4; ++fn)
        #pragma unroll
        for (int ks = 0; ks < 2; ++ks)
          acc[fm][fn] = __builtin_amdgcn_mfma_f32_16x16x32_f16(
              af[fm * 2 + ks], bf[fn * 2 + ks], acc[fm][fn], 0, 0, 0);
    __syncthreads();                       // all reads done; smA/smB dead after loop
  }

  // C/D layout (m89-verified): col = lane&15, row = (lane>>4)*4 + reg
  const int rb = (lane >> 4) * 4;

  if (MODE == 0) {
    f16* C = (f16*)Call + (long)z * strideC;
    #pragma unroll
    for (int m = 0; m < 4; ++m)
      #pragma unroll
      for (int j = 0; j < 4; ++j) {
        long grow = brow + wm * 64 + m * 16 + rb + j;
        #pragma unroll
        for (int n = 0; n < 4; ++n) {
          long gcol = bcol + wn * 64 + n * 16 + lr;
          C[grow * ldc + gcol] = (f16)acc[m][n][j];
        }
      }
  } else if (MODE == 1) {
    // --- LDS-bounced mask + P epilogue (128x128 f16 tile = 32 KiB exactly) ---
    // col-swizzle ((r&7)<<3): 8-f16 granule; separates 4-apart row groups into
    // different banks; 8-apart rows 2-way (free). Bijective within 0..127.
    f16* smM = smbuf;
    const float* mask = maskAll + (long)z * strideMask;
    // coalesced mask stage: per thread 8 x (8 fp32 -> f16x8); 2KB/wave-instr
    #pragma unroll
    for (int i = 0; i < 8; ++i) {
      int e = i * 2048 + tid * 8;
      int r = e >> 7, c = e & 127;
      const float* s = mask + (brow + r) * (long)ldc + bcol + c;
      float4 lo = *(const float4*)s, hi = *(const float4*)(s + 4);
      f16x8 o;
      o[0] = (f16)lo.x; o[1] = (f16)lo.y; o[2] = (f16)lo.z; o[3] = (f16)lo.w;
      o[4] = (f16)hi.x; o[5] = (f16)hi.y; o[6] = (f16)hi.z; o[7] = (f16)hi.w;
      *(f16x8*)(smM + r * 128 + (c ^ ((r & 7) << 3))) = o;
    }
    __syncthreads();
    // compute p from acc + LDS mask; overwrite mask slot with p (same thread,
    // same slot -> no race); accumulate row sums as before
    #pragma unroll
    for (int m = 0; m < 4; ++m)
      #pragma unroll
      for (int j = 0; j < 4; ++j) {
        int lrow = wm * 64 + m * 16 + rb + j;
        float s = 0.f;
        #pragma unroll
        for (int n = 0; n < 4; ++n) {
          int lcol = wn * 64 + n * 16 + lr;
          int a = lrow * 128 + (lcol ^ ((lrow & 7) << 3));
          float p = __expf(acc[m][n][j] * scale + (float)smM[a]);
          smM[a] = (f16)p;
          s += p;
        }
        s += __shfl_xor(s, 1);
        s += __shfl_xor(s, 2);
        s += __shfl_xor(s, 4);
        s += __shfl_xor(s, 8);
        if (lr == 0)
          lvec[((long)z * M + brow + lrow) * 32 + bx * 2 + wn] = s;
      }
    __syncthreads();
    // coalesced P store: per thread 8 x f16x8; 1KB/wave-instr
    f16* C = (f16*)Call + (long)z * strideC;
    #pragma unroll
    for (int i = 0; i < 8; ++i) {
      int e = i * 2048 + tid * 8;
      int r = e >> 7, c = e & 127;
      f16x8 o = *(const f16x8*)(smM + r * 128 + (c ^ ((r & 7) << 3)));
      *(f16x8*)(C + (brow + r) * (long)ldc + bcol + c) = o;
    }
  } else {
    // --- LDS-bounced out epilogue: two 64x128 fp32 half-tiles (32 KiB each) ---
    // col-swizzle ((r&7)<<2): 4-float granule; 4-apart rows -> different banks.
    float* smO = (float*)smbuf;
    float* C = (float*)Call + (long)z * strideC;
    #pragma unroll
    for (int h = 0; h < 2; ++h) {
      if (wm == h) {
        #pragma unroll
        for (int m = 0; m < 4; ++m)
          #pragma unroll
          for (int j = 0; j < 4; ++j) {
            int lrh = m * 16 + rb + j;        // row within half-tile
            float inv = 1.0f / lvec[(long)z * M + brow + h * 64 + lrh];
            #pragma unroll
            for (int n = 0; n < 4; ++n) {
              int lcol = wn * 64 + n * 16 + lr;
              smO[lrh * 128 + (lcol ^ ((lrh & 7) << 2))] = acc[m][n][j] * inv;
            }
          }
      }
      __syncthreads();
      // coalesced store: per thread 8 x float4; 1KB/wave-instr
      #pragma unroll
      for (int i = 0; i < 8; ++i) {
        int e = i * 1024 + tid * 4;
        int r = e >> 7, c = e & 127;
        float4 o = *(const float4*)(smO + r * 128 + (c ^ ((r & 7) << 2)));
        *(float4*)(C + (brow + h * 64 + r) * (long)ldc + bcol + c) = o;
      }
      if (h == 0) __syncthreads();          // protect smO before phase-2 overwrite
    }
  }
}

// grid-strided fp32->fp16 convert: q, k, v, Wv  (Wq/Wk handled by transW)
__global__ void cvt_all(const float* __restrict__ q, const float* __restrict__ k,
                        const float* __restrict__ v, const float* __restrict__ Wv,
                        f16* __restrict__ qf, f16* __restrict__ kf, f16* __restrict__ vf,
                        f16* __restrict__ Wvf)
{
  const long NQ4 = 4194304, NW4 = 262144;       // float4 counts
  const long total = 3 * NQ4 + NW4;
  for (long i = (long)blockIdx.x * blockDim.x + threadIdx.x; i < total;
       i += (long)gridDim.x * blockDim.x) {
    const float* src; f16* dst; long j = i;
    if      (j <     NQ4) { src = q;  dst = qf; }
    else if (j < 2 * NQ4) { src = k;  dst = kf;  j -= NQ4; }
    else if (j < 3 * NQ4) { src = v;  dst = vf;  j -= 2 * NQ4; }
    else                  { src = Wv; dst = Wvf; j -= 3 * NQ4; }
    float4 vv = ((const float4*)src)[j];
    f16x4 o;
    o[0] = (f16)vv.x; o[1] = (f16)vv.y; o[2] = (f16)vv.z; o[3] = (f16)vv.w;
    ((f16x4*)dst)[j] = o;
  }
}

// 64x64-tile LDS transpose + fp32->fp16: WT[d][h] = (f16)W[h][d], for Wq and Wk.
__global__ void transW(const float* __restrict__ Wq, const float* __restrict__ Wk,
                       f16* __restrict__ WqT, f16* __restrict__ WkT)
{
  __shared__ f16 t[64][65];
  const float* W  = blockIdx.z ? Wk : Wq;
  f16*         WT = blockIdx.z ? WkT : WqT;
  const int h0 = blockIdx.y * 64, d0 = blockIdx.x * 64;
  const int tx = threadIdx.x & 15, ty = threadIdx.x >> 4;   // 16 x 16
  #pragma unroll
  for (int p = 0; p < 4; ++p) {
    int h = ty + p * 16;
    float4 vv = *(const float4*)(W + (long)(h0 + h) * 1024 + d0 + tx * 4);
    t[tx * 4 + 0][h] = (f16)vv.x;
    t[tx * 4 + 1][h] = (f16)vv.y;
    t[tx * 4 + 2][h] = (f16)vv.z;
    t[tx * 4 + 3][h] = (f16)vv.w;
  }
  __syncthreads();
  #pragma unroll
  for (int p = 0; p < 4; ++p) {
    int d = ty + p * 16;
    f16x4 o;
    o[0] = t[d][tx * 4 + 0];
    o[1] = t[d][tx * 4 + 1];
    o[2] = t[d][tx * 4 + 2];
    o[3] = t[d][tx * 4 + 3];
    *(f16x4*)(WT + (long)(d0 + d) * 1024 + h0 + tx * 4) = o;
  }
}

__global__ void reduce_l(const float* __restrict__ lpart, float* __restrict__ lsum, int n) {
  int i = blockIdx.x * blockDim.x + threadIdx.x;
  if (i < n) {
    float s = 0.f;
    #pragma unroll
    for (int j = 0; j < 32; ++j) s += lpart[(long)i * 32 + j];
    lsum[i] = s;
  }
}

extern "C" void kernel_launch(void* const* d_in, const int* in_sizes, int n_in,
                              void* d_out, int out_size, void* d_ws, size_t ws_size,
                              hipStream_t stream)
{
  const float* q    = (const float*)d_in[0];
  const float* k    = (const float*)d_in[1];
  const float* v    = (const float*)d_in[2];
  const float* mask = (const float*)d_in[3];
  const float* Wq   = (const float*)d_in[4];
  const float* Wk   = (const float*)d_in[5];
  const float* Wv   = (const float*)d_in[6];
  float* out = (float*)d_out;
  char*  ws  = (char*)d_ws;

  // workspace layout (bytes). qf and vf are dead after qg/vpT -> Pm overwrites
  // [0,64MB) = qf+vf. kf (needed by scores) lives above that region.
  f16*   qf    = (f16*)(ws + 0);           // 32 MB   (dead after qg)
  f16*   vf    = (f16*)(ws + 33554432);    // 32 MB   (dead after vpT)
  f16*   Pm    = (f16*)(ws + 0);           // 64 MB   (over qf+vf)
  f16*   kf    = (f16*)(ws + 67108864);    // 32 MB   (raw k fp16, read by scores)
  f16*   Wvf   = (f16*)(ws + 100663296);   // 2 MB
  f16*   WqT   = (f16*)(ws + 102760448);   // 2 MB    WqT[d][h]
  f16*   WkT   = (f16*)(ws + 104857600);   // 2 MB    WkT[d][h]
  f16*   Gt    = (f16*)(ws + 106954752);   // 2 MB    Gt[d'][d] = sum_h Wk[h,d']Wq[h,d]
  f16*   qg    = (f16*)(ws + 109051904);   // 32 MB   qg[l,d'] = sum_d q[l,d] G[d,d']
  f16*   vpT   = (f16*)(ws + 142606336);   // 32 MB   (stored H x J, transposed)
  float* lpart = (float*)(ws + 176160768); // 2 MB
  float* lsum  = (float*)(ws + 178257920); // 64 KB

  const long L = 2048, J = 2048, D = 1024, H = 1024;

  // 1) converts: q,k,v,Wv fp32->fp16 ; Wq,Wk fp32->fp16 TRANSPOSED
  cvt_all<<<dim3(2048), dim3(256), 0, stream>>>(q, k, v, Wv, qf, kf, vf, Wvf);
  transW<<<dim3(16, 16, 2), dim3(256), 0, stream>>>(Wq, Wk, WqT, WkT);

  // 2) Gt[d',d] = sum_h WkT[d',h] * WqT[d,h]   M=N=K=1024 (tiny, 2.1 GF)
  gemm_bt<0><<<dim3(1024 / BN, 1024 / BM, 1), dim3(256), 0, stream>>>(
      WkT, WqT, Gt, 1024, 1024, 1024, 1024, 1024, 1024,
      0, 0, 0, nullptr, 0, nullptr, 0.f);

  // 3) qg[l,d'] = sum_d qf[l,d] * Gt[d',d]   M=16384 N=1024 K=1024
  gemm_bt<0><<<dim3(1024 / BN, 16384 / BM, 1), dim3(256), 0, stream>>>(
      qf, Gt, qg, 16384, 1024, 1024, 1024, 1024, 1024,
      0, 0, 0, nullptr, 0, nullptr, 0.f);

  // 4) vpT[b][h,j] = sum_d Wv[h,d] * v[b][j,d]   M=1024 N=2048 K=1024, batched
  gemm_bt<0><<<dim3(2048 / BN, 1024 / BM, 8), dim3(256), 0, stream>>>(
      Wvf, vf, vpT, 1024, 2048, 1024, 1024, 1024, 2048,
      0, J * D, H * J, nullptr, 0, nullptr, 0.f);

  // 5) P[b][l,j] = exp(qg.kf^T / 32 + mask), fp16, + row-sum partials
  //    (scores = qp.kp^T by associativity: qg = q.Wq^T.Wk, kf = raw k)
  gemm_bt<1><<<dim3(2048 / BN, 2048 / BM, 8), dim3(256), 0, stream>>>(
      qg, kf, Pm, 2048, 2048, 1024, 1024, 1024, 2048,
      L * D, J * D, L * J, mask, L * J, lpart, 0.03125f);

  reduce_l<<<dim3(16384 / 256), dim3(256), 0, stream>>>(lpart, lsum, 16384);

  // 6) out[b][l,h] = (sum_j P[l,j] * vpT[h,j]) / l[b,l]   M=2048 N=1024 K=2048
  gemm_bt<2><<<dim3(1024 / BN, 2048 / BM, 8), dim3(256), 0, stream>>>(
      Pm, vpT, out, 2048, 1024, 2048, 2048, 2048, 1024,
      L * J, H * J, L * H, nullptr, 0, lsum, 0.f);
}

// Round 16
// 330.559 us; speedup vs baseline: 1.1581x; 1.0062x over previous
//
#include <hip/hip_runtime.h>
#include <hip/hip_fp16.h>

typedef _Float16 f16;
typedef __attribute__((ext_vector_type(8))) _Float16 f16x8;
typedef __attribute__((ext_vector_type(4))) _Float16 f16x4;
typedef __attribute__((ext_vector_type(4))) float f32x4;

#define BM 128
#define BN 128
#define BK 64

__device__ __forceinline__ void gll16(const void* src, void* dst) {
  __builtin_amdgcn_global_load_lds((const __attribute__((address_space(1))) void*)src,
                                   (__attribute__((address_space(3))) void*)dst,
                                   16, 0, 0);
}

// Logical GEMM descriptor: C[m,n] = sum_k A[m,k]*B[n,k] ("BT" form), batched over gz.
struct GArgs {
  const f16* A; const f16* B; void* C;
  int M, N, K, lda, ldb, ldc;
  long sA, sB, sC;
  const float* mask; long sMask;
  float* lpart; float scale;
  unsigned gx, gy, gz;            // logical grid (N/BN, M/BM, batch)
};

// m97-replica K-loop (R8/R11/R14 proven optimum) + R15 LDS-bounced epilogues.
// 128x128 tile, BK=64, single-buffered 32 KiB LDS, 256 thr (4 waves, 64x64/wave),
// 2 barriers/K-tile; vmcnt drain covered by 3 blocks/CU cross-block overlap (m114;
// hard residency cap measured R10/R11). Swizzle: linear slot s of row r holds
// global slot s^(r&7) (0 conflicts measured). R16: body refactored to take a
// flat block id so independent GEMMs can share one dispatch (tail-fill).
// MODE 0: C fp16   MODE 1: P=exp(acc*scale+mask) fp16 + row-sum partials (32/row)
// MODE 2: C fp32 = acc * invsum (invsum computed in-prologue from lpart)
template<int MODE>
__device__ __forceinline__ void gemm_body(const GArgs ga, unsigned fid,
                                          f16* smbuf, float* smL)
{
  f16* smA = smbuf;
  f16* smB = smbuf + BM * BK;

  // T1: bijective XCD-aware remap within the logical grid (nwg % 8 == 0 always)
  unsigned nwg = ga.gx * ga.gy * ga.gz;
  unsigned swz = (fid & 7) * (nwg >> 3) + (fid >> 3);
  unsigned bx = swz % ga.gx, rem = swz / ga.gx;
  unsigned by = rem % ga.gy, bz = rem / ga.gy;

  const int z = bz;
  const f16* A = ga.A + (long)z * ga.sA;
  const f16* B = ga.B + (long)z * ga.sB;

  const int tid  = threadIdx.x;
  const int wid  = tid >> 6;
  const int lane = tid & 63;
  const int wm = wid >> 1;        // 0..1 -> 64 rows of C
  const int wn = wid & 1;         // 0..1 -> 64 cols of C
  const int lr = lane & 15;
  const int g  = lane >> 4;       // k-slot 0..3 (8 f16 each)

  const long brow = (long)by * BM;
  const long bcol = (long)bx * BN;
  const int  nt   = ga.K / BK;

  // MODE2 prologue: per-block row inverse-sums from lpart (replaces reduce_l).
  // Sequential add order matches the old reduce_l (bitwise-identical results).
  if (MODE == 2) {
    if (tid < 128) {
      const float* lp = ga.lpart + ((long)z * ga.M + brow + tid) * 32;
      float s = 0.f;
      #pragma unroll
      for (int j = 0; j < 32; ++j) s += lp[j];
      smL[tid] = 1.0f / s;
    }
    // first K-loop __syncthreads publishes smL before any epilogue read
  }

  f32x4 acc[4][4] = {};

  auto stA = [&](int t) {
    #pragma unroll
    for (int i = 0; i < 4; ++i) {
      int c  = i * 256 + tid;
      int r  = c >> 3;
      int sl = (c & 7) ^ (r & 7);
      gll16(A + (brow + r) * (long)ga.lda + t * BK + sl * 8, &smA[c * 8]);
    }
  };
  auto stB = [&](int t) {
    #pragma unroll
    for (int i = 0; i < 4; ++i) {
      int c  = i * 256 + tid;
      int r  = c >> 3;
      int sl = (c & 7) ^ (r & 7);
      gll16(B + (bcol + r) * (long)ga.ldb + t * BK + sl * 8, &smB[c * 8]);
    }
  };

  for (int t = 0; t < nt; ++t) {
    stA(t); stB(t);
    __syncthreads();                       // compiler drains vmcnt before s_barrier
    f16x8 af[8], bf[8];
    #pragma unroll
    for (int fm = 0; fm < 4; ++fm)
      #pragma unroll
      for (int ks = 0; ks < 2; ++ks) {
        int r = wm * 64 + fm * 16 + lr;
        af[fm * 2 + ks] = *(const f16x8*)(smA + r * BK + ((ks * 4 + g) ^ (r & 7)) * 8);
      }
    #pragma unroll
    for (int fn = 0; fn < 4; ++fn)
      #pragma unroll
      for (int ks = 0; ks < 2; ++ks) {
        int r = wn * 64 + fn * 16 + lr;
        bf[fn * 2 + ks] = *(const f16x8*)(smB + r * BK + ((ks * 4 + g) ^ (r & 7)) * 8);
      }
    #pragma unroll
    for (int fm = 0; fm < 4; ++fm)
      #pragma unroll
      for (int fn = 0; fn < 4; ++fn)
        #pragma unroll
        for (int ks = 0; ks < 2; ++ks)
          acc[fm][fn] = __builtin_amdgcn_mfma_f32_16x16x32_f16(
              af[fm * 2 + ks], bf[fn * 2 + ks], acc[fm][fn], 0, 0, 0);
    __syncthreads();                       // all reads done; smA/smB dead after loop
  }

  // C/D layout (m89-verified): col = lane&15, row = (lane>>4)*4 + reg
  const int rb = (lane >> 4) * 4;

  if (MODE == 0) {
    f16* C = (f16*)ga.C + (long)z * ga.sC;
    #pragma unroll
    for (int m = 0; m < 4; ++m)
      #pragma unroll
      for (int j = 0; j < 4; ++j) {
        long grow = brow + wm * 64 + m * 16 + rb + j;
        #pragma unroll
        for (int n = 0; n < 4; ++n) {
          long gcol = bcol + wn * 64 + n * 16 + lr;
          C[grow * ga.ldc + gcol] = (f16)acc[m][n][j];
        }
      }
  } else if (MODE == 1) {
    // LDS-bounced mask + P epilogue (128x128 f16 = 32 KiB); col ^= (r&7)<<3
    f16* smM = smbuf;
    const float* mask = ga.mask + (long)z * ga.sMask;
    #pragma unroll
    for (int i = 0; i < 8; ++i) {
      int e = i * 2048 + tid * 8;
      int r = e >> 7, c = e & 127;
      const float* s = mask + (brow + r) * (long)ga.ldc + bcol + c;
      float4 lo = *(const float4*)s, hi = *(const float4*)(s + 4);
      f16x8 o;
      o[0] = (f16)lo.x; o[1] = (f16)lo.y; o[2] = (f16)lo.z; o[3] = (f16)lo.w;
      o[4] = (f16)hi.x; o[5] = (f16)hi.y; o[6] = (f16)hi.z; o[7] = (f16)hi.w;
      *(f16x8*)(smM + r * 128 + (c ^ ((r & 7) << 3))) = o;
    }
    __syncthreads();
    #pragma unroll
    for (int m = 0; m < 4; ++m)
      #pragma unroll
      for (int j = 0; j < 4; ++j) {
        int lrow = wm * 64 + m * 16 + rb + j;
        float s = 0.f;
        #pragma unroll
        for (int n = 0; n < 4; ++n) {
          int lcol = wn * 64 + n * 16 + lr;
          int a = lrow * 128 + (lcol ^ ((lrow & 7) << 3));
          float p = __expf(acc[m][n][j] * ga.scale + (float)smM[a]);
          smM[a] = (f16)p;
          s += p;
        }
        s += __shfl_xor(s, 1);
        s += __shfl_xor(s, 2);
        s += __shfl_xor(s, 4);
        s += __shfl_xor(s, 8);
        if (lr == 0)
          ga.lpart[((long)z * ga.M + brow + lrow) * 32 + bx * 2 + wn] = s;
      }
    __syncthreads();
    f16* C = (f16*)ga.C + (long)z * ga.sC;
    #pragma unroll
    for (int i = 0; i < 8; ++i) {
      int e = i * 2048 + tid * 8;
      int r = e >> 7, c = e & 127;
      f16x8 o = *(const f16x8*)(smM + r * 128 + (c ^ ((r & 7) << 3)));
      *(f16x8*)(C + (brow + r) * (long)ga.ldc + bcol + c) = o;
    }
  } else {
    // LDS-bounced out epilogue: two 64x128 fp32 half-tiles; col ^= (r&7)<<2
    float* smO = (float*)smbuf;
    float* C = (float*)ga.C + (long)z * ga.sC;
    #pragma unroll
    for (int h = 0; h < 2; ++h) {
      if (wm == h) {
        #pragma unroll
        for (int m = 0; m < 4; ++m)
          #pragma unroll
          for (int j = 0; j < 4; ++j) {
            int lrh = m * 16 + rb + j;
            float inv = smL[h * 64 + lrh];
            #pragma unroll
            for (int n = 0; n < 4; ++n) {
              int lcol = wn * 64 + n * 16 + lr;
              smO[lrh * 128 + (lcol ^ ((lrh & 7) << 2))] = acc[m][n][j] * inv;
            }
          }
      }
      __syncthreads();
      #pragma unroll
      for (int i = 0; i < 8; ++i) {
        int e = i * 1024 + tid * 4;
        int r = e >> 7, c = e & 127;
        float4 o = *(const float4*)(smO + r * 128 + (c ^ ((r & 7) << 2)));
        *(float4*)(C + (brow + h * 64 + r) * (long)ga.ldc + bcol + c) = o;
      }
      if (h == 0) __syncthreads();
    }
  }
}

template<int MODE>
__global__ __launch_bounds__(256, 3)
void gemm_single(GArgs ga)
{
  __shared__ __align__(16) f16 smbuf[BM * BK + BN * BK];   // 32 KiB
  __shared__ float smL[128];
  gemm_body<MODE>(ga, blockIdx.x, smbuf, smL);
}

// Two independent GEMMs co-dispatched for tail-fill (3 blocks/CU => 768
// concurrent; 1024+1024 separate = 2x(768+256) rounds; fused 2048 = 768+768+512).
__global__ __launch_bounds__(256, 3)
void gemm_dual0(GArgs a0, GArgs a1, unsigned n0)
{
  __shared__ __align__(16) f16 smbuf[BM * BK + BN * BK];
  unsigned fid = blockIdx.x;
  if (fid < n0) gemm_body<0>(a0, fid, smbuf, nullptr);
  else          gemm_body<0>(a1, fid - n0, smbuf, nullptr);
}

// Fused: blocks 0..511 = transW (Wq/Wk fp32->fp16 transposed), rest = cvt
// grid-stride (q,k,v,Wv fp32->fp16). Independent halves.
__global__ void cvt_trans(const float* __restrict__ q, const float* __restrict__ k,
                          const float* __restrict__ v, const float* __restrict__ Wq,
                          const float* __restrict__ Wk, const float* __restrict__ Wv,
                          f16* __restrict__ qf, f16* __restrict__ kf, f16* __restrict__ vf,
                          f16* __restrict__ Wvf, f16* __restrict__ WqT, f16* __restrict__ WkT)
{
  __shared__ f16 t[64][65];
  const unsigned bid = blockIdx.x;
  if (bid < 512) {
    const float* W  = (bid & 256) ? Wk : Wq;
    f16*         WT = (bid & 256) ? WkT : WqT;
    const int h0 = ((bid >> 4) & 15) * 64, d0 = (bid & 15) * 64;
    const int tx = threadIdx.x & 15, ty = threadIdx.x >> 4;   // 16 x 16
    #pragma unroll
    for (int p = 0; p < 4; ++p) {
      int h = ty + p * 16;
      float4 vv = *(const float4*)(W + (long)(h0 + h) * 1024 + d0 + tx * 4);
      t[tx * 4 + 0][h] = (f16)vv.x;
      t[tx * 4 + 1][h] = (f16)vv.y;
      t[tx * 4 + 2][h] = (f16)vv.z;
      t[tx * 4 + 3][h] = (f16)vv.w;
    }
    __syncthreads();
    #pragma unroll
    for (int p = 0; p < 4; ++p) {
      int d = ty + p * 16;
      f16x4 o;
      o[0] = t[d][tx * 4 + 0];
      o[1] = t[d][tx * 4 + 1];
      o[2] = t[d][tx * 4 + 2];
      o[3] = t[d][tx * 4 + 3];
      *(f16x4*)(WT + (long)(d0 + d) * 1024 + h0 + tx * 4) = o;
    }
  } else {
    const long NQ4 = 4194304, NW4 = 262144;       // float4 counts
    const long total = 3 * NQ4 + NW4;
    const long nb = 2048;
    for (long i = (long)(bid - 512) * 256 + threadIdx.x; i < total; i += nb * 256) {
      const float* src; f16* dst; long j = i;
      if      (j <     NQ4) { src = q;  dst = qf; }
      else if (j < 2 * NQ4) { src = k;  dst = kf;  j -= NQ4; }
      else if (j < 3 * NQ4) { src = v;  dst = vf;  j -= 2 * NQ4; }
      else                  { src = Wv; dst = Wvf; j -= 3 * NQ4; }
      float4 vv = ((const float4*)src)[j];
      f16x4 o;
      o[0] = (f16)vv.x; o[1] = (f16)vv.y; o[2] = (f16)vv.z; o[3] = (f16)vv.w;
      ((f16x4*)dst)[j] = o;
    }
  }
}

extern "C" void kernel_launch(void* const* d_in, const int* in_sizes, int n_in,
                              void* d_out, int out_size, void* d_ws, size_t ws_size,
                              hipStream_t stream)
{
  const float* q    = (const float*)d_in[0];
  const float* k    = (const float*)d_in[1];
  const float* v    = (const float*)d_in[2];
  const float* mask = (const float*)d_in[3];
  const float* Wq   = (const float*)d_in[4];
  const float* Wk   = (const float*)d_in[5];
  const float* Wv   = (const float*)d_in[6];
  float* out = (float*)d_out;
  char*  ws  = (char*)d_ws;

  // workspace layout (bytes). qf and vf are dead after qg/vpT -> Pm overwrites
  // [0,64MB) = qf+vf. kf (needed by scores) lives above that region.
  f16*   qf    = (f16*)(ws + 0);           // 32 MB   (dead after qg)
  f16*   vf    = (f16*)(ws + 33554432);    // 32 MB   (dead after vpT)
  f16*   Pm    = (f16*)(ws + 0);           // 64 MB   (over qf+vf)
  f16*   kf    = (f16*)(ws + 67108864);    // 32 MB   (raw k fp16, read by scores)
  f16*   Wvf   = (f16*)(ws + 100663296);   // 2 MB
  f16*   WqT   = (f16*)(ws + 102760448);   // 2 MB    WqT[d][h]
  f16*   WkT   = (f16*)(ws + 104857600);   // 2 MB    WkT[d][h]
  f16*   Gt    = (f16*)(ws + 106954752);   // 2 MB    Gt[d'][d] = sum_h Wk[h,d']Wq[h,d]
  f16*   qg    = (f16*)(ws + 109051904);   // 32 MB   qg[l,d'] = sum_d q[l,d] G[d,d']
  f16*   vpT   = (f16*)(ws + 142606336);   // 32 MB   (stored H x J, transposed)
  float* lpart = (float*)(ws + 176160768); // 2 MB

  // 1) converts + weight transposes, one dispatch (independent halves)
  cvt_trans<<<dim3(2560), dim3(256), 0, stream>>>(
      q, k, v, Wq, Wk, Wv, qf, kf, vf, Wvf, WqT, WkT);

  // 2) Gt[d',d] = sum_h WkT[d',h] * WqT[d,h]   M=N=K=1024 (64 blocks)
  GArgs aGt = { WkT, WqT, Gt, 1024, 1024, 1024, 1024, 1024, 1024,
                0, 0, 0, nullptr, 0, nullptr, 0.f, 8, 8, 1 };
  gemm_single<0><<<dim3(64), dim3(256), 0, stream>>>(aGt);

  // 3) fused dual: qg[l,d'] = sum_d qf[l,d]*Gt[d',d]  (M=16384,N=1024,K=1024)
  //              + vpT[b][h,j] = sum_d Wvf[h,d]*vf[b][j,d] (M=1024,N=2048,K=1024,b=8)
  GArgs aQg  = { qf, Gt, qg, 16384, 1024, 1024, 1024, 1024, 1024,
                 0, 0, 0, nullptr, 0, nullptr, 0.f, 8, 128, 1 };
  GArgs aVpT = { Wvf, vf, vpT, 1024, 2048, 1024, 1024, 1024, 2048,
                 0, (long)2048 * 1024, (long)1024 * 2048, nullptr, 0, nullptr, 0.f,
                 16, 8, 8 };
  gemm_dual0<<<dim3(2048), dim3(256), 0, stream>>>(aQg, aVpT, 1024);

  // 4) scores: P[b][l,j] = exp(qg.kf^T/32 + mask), fp16 + row-sum partials
  GArgs aSc = { qg, kf, Pm, 2048, 2048, 1024, 1024, 1024, 2048,
                (long)2048 * 1024, (long)2048 * 1024, (long)2048 * 2048,
                mask, (long)2048 * 2048, lpart, 0.03125f, 16, 16, 8 };
  gemm_single<1><<<dim3(2048), dim3(256), 0, stream>>>(aSc);

  // 5) out[b][l,h] = (sum_j P[l,j]*vpT[h,j]) / lsum  (lsum folded into prologue)
  GArgs aPV = { Pm, vpT, out, 2048, 1024, 2048, 2048, 2048, 1024,
                (long)2048 * 2048, (long)1024 * 2048, (long)2048 * 1024,
                nullptr, 0, lpart, 0.f, 8, 16, 8 };
  gemm_single<2><<<dim3(1024), dim3(256), 0, stream>>>(aPV);
}